// Round 1
// baseline (1022.558 us; speedup 1.0000x reference)
//
#include <hip/hip_runtime.h>

#define N_NODES 50000
#define N_EDGES 800000
#define E_TOT   (N_EDGES + N_NODES)   // 850000, self-loops appended at the end
#define IN_C    128
#define OUT_C   64
#define NEG_SLOPE 0.2f

// ---- order-preserving float<->uint encoding for atomic max over floats ----
__device__ __forceinline__ unsigned enc_f(float f) {
    unsigned u = __float_as_uint(f);
    return (u & 0x80000000u) ? ~u : (u | 0x80000000u);
}
__device__ __forceinline__ float dec_f(unsigned u) {
    u = (u & 0x80000000u) ? (u & 0x7fffffffu) : ~u;
    return __uint_as_float(u);
}

__device__ __forceinline__ void atomAddF(float* p, float v) {
    unsafeAtomicAdd(p, v);   // hardware global_atomic_add_f32 on gfx950
}

// ---------------- kernel 1: x_l = x@W_l, x_r = x@W_r (fused) ----------------
// block = 256 threads, 32 nodes per block; x tile staged in LDS (16 KB).
__global__ __launch_bounds__(256) void k_gemm(
    const float* __restrict__ x, const float* __restrict__ Wl,
    const float* __restrict__ Wr, float* __restrict__ xl, float* __restrict__ xr)
{
    __shared__ float xs[32 * IN_C];
    const int tid = threadIdx.x;
    const int nbase = blockIdx.x * 32;

    const float4* x4 = (const float4*)x;
    float4* xs4 = (float4*)xs;
    // 32 rows * 128 floats = 1024 float4 loads, 4 per thread, coalesced
    for (int i = tid; i < 1024; i += 256) {
        int row = i >> 5;            // 32 float4 per row
        int node = nbase + row;
        float4 v = make_float4(0.f, 0.f, 0.f, 0.f);
        if (node < N_NODES) v = x4[(size_t)node * 32 + (i & 31)];
        xs4[i] = v;
    }
    __syncthreads();

    const int c  = tid & 63;         // output channel (coalesced stores)
    const int nb = (tid >> 6) * 8;   // 8 nodes per thread (wave-uniform -> LDS broadcast)
    float accl[8], accr[8];
#pragma unroll
    for (int i = 0; i < 8; ++i) { accl[i] = 0.f; accr[i] = 0.f; }

    for (int k = 0; k < IN_C; ++k) {
        float wl = Wl[k * 64 + c];
        float wr = Wr[k * 64 + c];
#pragma unroll
        for (int i = 0; i < 8; ++i) {
            float xv = xs[(nb + i) * IN_C + k];   // same addr across wave: broadcast
            accl[i] = fmaf(xv, wl, accl[i]);
            accr[i] = fmaf(xv, wr, accr[i]);
        }
    }
#pragma unroll
    for (int i = 0; i < 8; ++i) {
        int node = nbase + nb + i;
        if (node < N_NODES) {
            xl[(size_t)node * 64 + c] = accl[i];
            xr[(size_t)node * 64 + c] = accr[i];
        }
    }
}

// ------- kernel 2: per-edge logit = att . leaky_relu(xl[src]+xr[dst]) -------
// one thread per edge; float4 row gathers (L2-resident); atomicMax segment max
__global__ __launch_bounds__(256) void k_logit(
    const int* __restrict__ ei, const float* __restrict__ xl,
    const float* __restrict__ xr, const float* __restrict__ att,
    float* __restrict__ logit, unsigned* __restrict__ menc)
{
    __shared__ float att_s[64];
    if (threadIdx.x < 64) att_s[threadIdx.x] = att[threadIdx.x];
    __syncthreads();

    int e = blockIdx.x * 256 + threadIdx.x;
    if (e >= E_TOT) return;
    int src, dst;
    if (e < N_EDGES) { src = ei[e]; dst = ei[N_EDGES + e]; }
    else             { src = dst = e - N_EDGES; }

    const float4* a4 = (const float4*)(xl + (size_t)src * 64);
    const float4* b4 = (const float4*)(xr + (size_t)dst * 64);
    const float4* t4 = (const float4*)att_s;
    float acc = 0.f;
#pragma unroll
    for (int i = 0; i < 16; ++i) {
        float4 a = a4[i], b = b4[i], t = t4[i];
        float s;
        s = a.x + b.x; acc = fmaf(t.x, (s > 0.f ? s : NEG_SLOPE * s), acc);
        s = a.y + b.y; acc = fmaf(t.y, (s > 0.f ? s : NEG_SLOPE * s), acc);
        s = a.z + b.z; acc = fmaf(t.z, (s > 0.f ? s : NEG_SLOPE * s), acc);
        s = a.w + b.w; acc = fmaf(t.w, (s > 0.f ? s : NEG_SLOPE * s), acc);
    }
    logit[e] = acc;
    atomicMax(&menc[dst], enc_f(acc));
}

// ---------- kernel 3: a = exp(logit - m[dst]); denom[dst] += a ----------
__global__ __launch_bounds__(256) void k_exp(
    const int* __restrict__ ei, const float* __restrict__ logit,
    const unsigned* __restrict__ menc, float* __restrict__ aexp,
    float* __restrict__ denom)
{
    int e = blockIdx.x * 256 + threadIdx.x;
    if (e >= E_TOT) return;
    int dst = (e < N_EDGES) ? ei[N_EDGES + e] : e - N_EDGES;
    float m = dec_f(menc[dst]);
    float a = __expf(logit[e] - m);
    aexp[e] = a;
    atomAddF(&denom[dst], a);
}

// ------- kernel 4: acc[dst] += a_e * xl[src]  (division deferred) -------
// 16 threads per edge, 4 channels each -> coalesced 256B gather per edge
__global__ __launch_bounds__(256) void k_scatter(
    const int* __restrict__ ei, const float* __restrict__ xl,
    const float* __restrict__ aexp, float* __restrict__ acc)
{
    int t = blockIdx.x * 256 + threadIdx.x;
    int e = t >> 4;
    if (e >= E_TOT) return;
    int g = t & 15;
    int src, dst;
    if (e < N_EDGES) { src = ei[e]; dst = ei[N_EDGES + e]; }
    else             { src = dst = e - N_EDGES; }
    float a = aexp[e];
    float4 v = ((const float4*)(xl + (size_t)src * 64))[g];
    float* o = acc + (size_t)dst * 64 + g * 4;
    atomAddF(o + 0, a * v.x);
    atomAddF(o + 1, a * v.y);
    atomAddF(o + 2, a * v.z);
    atomAddF(o + 3, a * v.w);
}

// ------ kernel 5: h = elu(acc/denom + bias); out = log_softmax(h) ------
// one 64-lane wave per node, in-place on d_out
__global__ __launch_bounds__(256) void k_final(
    const float* __restrict__ acc, const float* __restrict__ denom,
    const float* __restrict__ bias, float* __restrict__ out)
{
    int t = blockIdx.x * 256 + threadIdx.x;
    int n = t >> 6;
    if (n >= N_NODES) return;
    int c = t & 63;
    float d = denom[n] + 1e-16f;
    float h = acc[t] / d + bias[c];
    h = (h > 0.f) ? h : (__expf(h) - 1.f);          // ELU
    float mx = h;
#pragma unroll
    for (int o = 32; o > 0; o >>= 1) mx = fmaxf(mx, __shfl_xor(mx, o, 64));
    float ex = __expf(h - mx);
    float sum = ex;
#pragma unroll
    for (int o = 32; o > 0; o >>= 1) sum += __shfl_xor(sum, o, 64);
    out[t] = h - mx - __logf(sum);
}

extern "C" void kernel_launch(void* const* d_in, const int* in_sizes, int n_in,
                              void* d_out, int out_size, void* d_ws, size_t ws_size,
                              hipStream_t stream)
{
    const float* x    = (const float*)d_in[0];
    const int*   ei   = (const int*)  d_in[1];   // int32 per harness convention
    const float* Wl   = (const float*)d_in[2];
    const float* Wr   = (const float*)d_in[3];
    const float* att  = (const float*)d_in[4];
    const float* bias = (const float*)d_in[5];
    float* out = (float*)d_out;

    char* w = (char*)d_ws;
    float*    xl    = (float*)w;    w += (size_t)N_NODES * 64 * 4;
    float*    xr    = (float*)w;    w += (size_t)N_NODES * 64 * 4;
    float*    logit = (float*)w;    w += (size_t)E_TOT * 4;
    float*    aexp  = (float*)w;    w += (size_t)E_TOT * 4;
    unsigned* menc  = (unsigned*)w; w += (size_t)N_NODES * 4;
    float*    denom = (float*)w;    w += (size_t)N_NODES * 4;

    // zero-init accumulators (harness poisons d_out/d_ws with 0xAA)
    hipMemsetAsync(menc,  0, (size_t)N_NODES * 4, stream);
    hipMemsetAsync(denom, 0, (size_t)N_NODES * 4, stream);
    hipMemsetAsync(out,   0, (size_t)N_NODES * 64 * 4, stream);

    k_gemm   <<<(N_NODES + 31) / 32,        256, 0, stream>>>(x, Wl, Wr, xl, xr);
    k_logit  <<<(E_TOT + 255) / 256,        256, 0, stream>>>(ei, xl, xr, att, logit, menc);
    k_exp    <<<(E_TOT + 255) / 256,        256, 0, stream>>>(ei, logit, menc, aexp, denom);
    k_scatter<<<(E_TOT * 16 + 255) / 256,   256, 0, stream>>>(ei, xl, aexp, out);
    k_final  <<<(N_NODES * 64) / 256,       256, 0, stream>>>(out, denom, bias, out);
}

// Round 2
// 361.596 us; speedup vs baseline: 2.8279x; 2.8279x over previous
//
#include <hip/hip_runtime.h>

#define N_NODES 50000
#define N_EDGES 800000
#define E_TOT   (N_EDGES + N_NODES)   // 850000, self-loops appended at the end
#define IN_C    128
#define OUT_C   64
#define NEG_SLOPE 0.2f

// ---------------- kernel 1: x_l = x@W_l, x_r = x@W_r (fused) ----------------
__global__ __launch_bounds__(256) void k_gemm(
    const float* __restrict__ x, const float* __restrict__ Wl,
    const float* __restrict__ Wr, float* __restrict__ xl, float* __restrict__ xr)
{
    __shared__ float xs[32 * IN_C];
    const int tid = threadIdx.x;
    const int nbase = blockIdx.x * 32;

    const float4* x4 = (const float4*)x;
    float4* xs4 = (float4*)xs;
    for (int i = tid; i < 1024; i += 256) {
        int row = i >> 5;
        int node = nbase + row;
        float4 v = make_float4(0.f, 0.f, 0.f, 0.f);
        if (node < N_NODES) v = x4[(size_t)node * 32 + (i & 31)];
        xs4[i] = v;
    }
    __syncthreads();

    const int c  = tid & 63;
    const int nb = (tid >> 6) * 8;
    float accl[8], accr[8];
#pragma unroll
    for (int i = 0; i < 8; ++i) { accl[i] = 0.f; accr[i] = 0.f; }

    for (int k = 0; k < IN_C; ++k) {
        float wl = Wl[k * 64 + c];
        float wr = Wr[k * 64 + c];
#pragma unroll
        for (int i = 0; i < 8; ++i) {
            float xv = xs[(nb + i) * IN_C + k];
            accl[i] = fmaf(xv, wl, accl[i]);
            accr[i] = fmaf(xv, wr, accr[i]);
        }
    }
#pragma unroll
    for (int i = 0; i < 8; ++i) {
        int node = nbase + nb + i;
        if (node < N_NODES) {
            xl[(size_t)node * 64 + c] = accl[i];
            xr[(size_t)node * 64 + c] = accr[i];
        }
    }
}

// ---- kernel 2: per-edge degree count; epos[e] = slot within dst segment ----
__global__ __launch_bounds__(256) void k_deg(
    const int* __restrict__ ei, int* __restrict__ deg, int* __restrict__ epos)
{
    int e = blockIdx.x * 256 + threadIdx.x;
    if (e >= E_TOT) return;
    int dst = (e < N_EDGES) ? ei[N_EDGES + e] : e - N_EDGES;
    epos[e] = atomicAdd(&deg[dst], 1);
}

// -------- kernel 3: single-block exclusive scan deg[N] -> off[N+1] ----------
__global__ __launch_bounds__(1024) void k_scan(
    const int* __restrict__ deg, int* __restrict__ off)
{
    __shared__ int part[1024];
    const int tid = threadIdx.x;
    const int CH = (N_NODES + 1023) / 1024;   // 49
    const int base = tid * CH;
    int s = 0;
    for (int i = 0; i < CH; ++i) {
        int idx = base + i;
        if (idx < N_NODES) s += deg[idx];
    }
    part[tid] = s;
    __syncthreads();
    // Hillis-Steele inclusive scan
    for (int o = 1; o < 1024; o <<= 1) {
        int v = (tid >= o) ? part[tid - o] : 0;
        __syncthreads();
        part[tid] += v;
        __syncthreads();
    }
    int run = (tid > 0) ? part[tid - 1] : 0;
    for (int i = 0; i < CH; ++i) {
        int idx = base + i;
        if (idx < N_NODES) { off[idx] = run; run += deg[idx]; }
    }
    if (tid == 1023) off[N_NODES] = part[1023];
}

// --- kernel 4: logits into CSR slots. 8 threads/edge, 32B gather per lane ---
__global__ __launch_bounds__(256) void k_csr_logit(
    const int* __restrict__ ei, const int* __restrict__ epos,
    const int* __restrict__ off, const float* __restrict__ xl,
    const float* __restrict__ xr, const float* __restrict__ att,
    float* __restrict__ csr_logit, int* __restrict__ csr_src)
{
    __shared__ float att_s[64];
    if (threadIdx.x < 64) att_s[threadIdx.x] = att[threadIdx.x];
    __syncthreads();

    int t = blockIdx.x * 256 + threadIdx.x;
    int e = t >> 3;
    if (e >= E_TOT) return;
    int g = t & 7;
    int src, dst;
    if (e < N_EDGES) { src = ei[e]; dst = ei[N_EDGES + e]; }
    else             { src = dst = e - N_EDGES; }

    const float4* a4 = (const float4*)(xl + (size_t)src * 64) + g * 2;
    const float4* b4 = (const float4*)(xr + (size_t)dst * 64) + g * 2;
    const float4* t4 = (const float4*)att_s + g * 2;
    float acc = 0.f;
#pragma unroll
    for (int i = 0; i < 2; ++i) {
        float4 a = a4[i], b = b4[i], tt = t4[i];
        float s;
        s = a.x + b.x; acc = fmaf(tt.x, (s > 0.f ? s : NEG_SLOPE * s), acc);
        s = a.y + b.y; acc = fmaf(tt.y, (s > 0.f ? s : NEG_SLOPE * s), acc);
        s = a.z + b.z; acc = fmaf(tt.z, (s > 0.f ? s : NEG_SLOPE * s), acc);
        s = a.w + b.w; acc = fmaf(tt.w, (s > 0.f ? s : NEG_SLOPE * s), acc);
    }
    // reduce across the aligned 8-lane group
    acc += __shfl_xor(acc, 1);
    acc += __shfl_xor(acc, 2);
    acc += __shfl_xor(acc, 4);
    if (g == 0) {
        int idx = off[dst] + epos[e];
        csr_logit[idx] = acc;
        csr_src[idx]   = src;
    }
}

// -- kernel 5: per-dst wave: softmax + weighted gather-sum + ELU + logsoftmax --
__global__ __launch_bounds__(256) void k_aggregate(
    const int* __restrict__ off, const int* __restrict__ csr_src,
    const float* __restrict__ csr_logit, const float* __restrict__ xl,
    const float* __restrict__ bias, float* __restrict__ out)
{
    int wid  = (blockIdx.x * 256 + threadIdx.x) >> 6;   // node id (wave-uniform)
    int lane = threadIdx.x & 63;                        // channel
    if (wid >= N_NODES) return;
    int o0 = off[wid], o1 = off[wid + 1];
    int deg = o1 - o0;

    float acc0 = 0.f, acc1 = 0.f, acc2 = 0.f, acc3 = 0.f, ssum;

    if (deg <= 64) {
        float l = (lane < deg) ? csr_logit[o0 + lane] : -INFINITY;
        float m = l;
#pragma unroll
        for (int o = 32; o > 0; o >>= 1) m = fmaxf(m, __shfl_xor(m, o));
        float a = (lane < deg) ? __expf(l - m) : 0.f;
        ssum = a;
#pragma unroll
        for (int o = 32; o > 0; o >>= 1) ssum += __shfl_xor(ssum, o);
        int srcv = (lane < deg) ? csr_src[o0 + lane] : 0;

        int i = 0;
        for (; i + 4 <= deg; i += 4) {   // 4 independent gathers in flight
            float a0 = __shfl(a, i),     a1 = __shfl(a, i + 1);
            float a2 = __shfl(a, i + 2), a3 = __shfl(a, i + 3);
            int s0 = __shfl(srcv, i),     s1 = __shfl(srcv, i + 1);
            int s2 = __shfl(srcv, i + 2), s3 = __shfl(srcv, i + 3);
            acc0 = fmaf(a0, xl[(size_t)s0 * 64 + lane], acc0);
            acc1 = fmaf(a1, xl[(size_t)s1 * 64 + lane], acc1);
            acc2 = fmaf(a2, xl[(size_t)s2 * 64 + lane], acc2);
            acc3 = fmaf(a3, xl[(size_t)s3 * 64 + lane], acc3);
        }
        for (; i < deg; ++i) {
            float ai = __shfl(a, i);
            int   si = __shfl(srcv, i);
            acc0 = fmaf(ai, xl[(size_t)si * 64 + lane], acc0);
        }
    } else {  // rare fallback (deg > 64): two-pass, recompute exp
        float m = -INFINITY;
        for (int i = lane; i < deg; i += 64) m = fmaxf(m, csr_logit[o0 + i]);
#pragma unroll
        for (int o = 32; o > 0; o >>= 1) m = fmaxf(m, __shfl_xor(m, o));
        float s0 = 0.f;
        for (int i = lane; i < deg; i += 64) s0 += __expf(csr_logit[o0 + i] - m);
        ssum = s0;
#pragma unroll
        for (int o = 32; o > 0; o >>= 1) ssum += __shfl_xor(ssum, o);
        for (int i = 0; i < deg; ++i) {
            float ai = __expf(csr_logit[o0 + i] - m);   // same-addr broadcast
            int   si = csr_src[o0 + i];
            acc0 = fmaf(ai, xl[(size_t)si * 64 + lane], acc0);
        }
    }
    float acc = (acc0 + acc1) + (acc2 + acc3);

    float h = acc / (ssum + 1e-16f) + bias[lane];
    h = (h > 0.f) ? h : (__expf(h) - 1.f);              // ELU
    float mx = h;
#pragma unroll
    for (int o = 32; o > 0; o >>= 1) mx = fmaxf(mx, __shfl_xor(mx, o));
    float ex = __expf(h - mx);
    float sm = ex;
#pragma unroll
    for (int o = 32; o > 0; o >>= 1) sm += __shfl_xor(sm, o);
    out[(size_t)wid * 64 + lane] = h - mx - __logf(sm);
}

extern "C" void kernel_launch(void* const* d_in, const int* in_sizes, int n_in,
                              void* d_out, int out_size, void* d_ws, size_t ws_size,
                              hipStream_t stream)
{
    const float* x    = (const float*)d_in[0];
    const int*   ei   = (const int*)  d_in[1];
    const float* Wl   = (const float*)d_in[2];
    const float* Wr   = (const float*)d_in[3];
    const float* att  = (const float*)d_in[4];
    const float* bias = (const float*)d_in[5];
    float* out = (float*)d_out;

    char* w = (char*)d_ws;
    float* xl        = (float*)w;  w += (size_t)N_NODES * 64 * 4;
    float* xr        = (float*)w;  w += (size_t)N_NODES * 64 * 4;
    float* csr_logit = (float*)w;  w += (size_t)E_TOT * 4;
    int*   csr_src   = (int*)w;    w += (size_t)E_TOT * 4;
    int*   epos      = (int*)w;    w += (size_t)E_TOT * 4;
    int*   deg       = (int*)w;    w += (size_t)N_NODES * 4;
    int*   off       = (int*)w;    w += (size_t)(N_NODES + 1) * 4;

    hipMemsetAsync(deg, 0, (size_t)N_NODES * 4, stream);

    k_gemm     <<<(N_NODES + 31) / 32,       256,  0, stream>>>(x, Wl, Wr, xl, xr);
    k_deg      <<<(E_TOT + 255) / 256,       256,  0, stream>>>(ei, deg, epos);
    k_scan     <<<1,                         1024, 0, stream>>>(deg, off);
    k_csr_logit<<<(E_TOT * 8 + 255) / 256,   256,  0, stream>>>(ei, epos, off, xl, xr, att, csr_logit, csr_src);
    k_aggregate<<<(N_NODES * 64 + 255) / 256,256,  0, stream>>>(off, csr_src, csr_logit, xl, bias, out);
}

// Round 3
// 281.929 us; speedup vs baseline: 3.6270x; 1.2826x over previous
//
#include <hip/hip_runtime.h>

#define N_NODES 50000
#define N_EDGES 800000
#define E_TOT   (N_EDGES + N_NODES)   // 850000, self-loops appended at the end
#define IN_C    128
#define OUT_C   64
#define NEG_SLOPE 0.2f

#define SCAN_CHUNK 512
#define SCAN_NB    ((N_NODES + SCAN_CHUNK - 1) / SCAN_CHUNK)   // 98

// ---------------- kernel 1: x_l = x@W_l, x_r = x@W_r (fused) ----------------
__global__ __launch_bounds__(256) void k_gemm(
    const float* __restrict__ x, const float* __restrict__ Wl,
    const float* __restrict__ Wr, float* __restrict__ xl, float* __restrict__ xr)
{
    __shared__ float xs[32 * IN_C];
    const int tid = threadIdx.x;
    const int nbase = blockIdx.x * 32;

    const float4* x4 = (const float4*)x;
    float4* xs4 = (float4*)xs;
    for (int i = tid; i < 1024; i += 256) {
        int row = i >> 5;
        int node = nbase + row;
        float4 v = make_float4(0.f, 0.f, 0.f, 0.f);
        if (node < N_NODES) v = x4[(size_t)node * 32 + (i & 31)];
        xs4[i] = v;
    }
    __syncthreads();

    const int c  = tid & 63;
    const int nb = (tid >> 6) * 8;
    float accl[8], accr[8];
#pragma unroll
    for (int i = 0; i < 8; ++i) { accl[i] = 0.f; accr[i] = 0.f; }

    for (int k = 0; k < IN_C; ++k) {
        float wl = Wl[k * 64 + c];
        float wr = Wr[k * 64 + c];
#pragma unroll
        for (int i = 0; i < 8; ++i) {
            float xv = xs[(nb + i) * IN_C + k];
            accl[i] = fmaf(xv, wl, accl[i]);
            accr[i] = fmaf(xv, wr, accr[i]);
        }
    }
#pragma unroll
    for (int i = 0; i < 8; ++i) {
        int node = nbase + nb + i;
        if (node < N_NODES) {
            xl[(size_t)node * 64 + c] = accl[i];
            xr[(size_t)node * 64 + c] = accr[i];
        }
    }
}

// ---- kernel 2: per-edge degree count; epos[e] = slot within dst segment ----
__global__ __launch_bounds__(256) void k_deg(
    const int* __restrict__ ei, int* __restrict__ deg, int* __restrict__ epos)
{
    int e = blockIdx.x * 256 + threadIdx.x;
    if (e >= E_TOT) return;
    int dst = (e < N_EDGES) ? ei[N_EDGES + e] : e - N_EDGES;
    epos[e] = atomicAdd(&deg[dst], 1);
}

// ---------------- 3-phase multi-block exclusive scan of deg ----------------
// phase A: per-block sums (coalesced)
__global__ __launch_bounds__(SCAN_CHUNK) void k_scan_pre(
    const int* __restrict__ deg, int* __restrict__ bsum)
{
    __shared__ int red[SCAN_CHUNK];
    int tid = threadIdx.x;
    int idx = blockIdx.x * SCAN_CHUNK + tid;
    red[tid] = (idx < N_NODES) ? deg[idx] : 0;
    __syncthreads();
#pragma unroll
    for (int o = SCAN_CHUNK / 2; o > 0; o >>= 1) {
        if (tid < o) red[tid] += red[tid + o];
        __syncthreads();
    }
    if (tid == 0) bsum[blockIdx.x] = red[0];
}

// phase B: single small block scans the 98 block sums
__global__ __launch_bounds__(128) void k_scan_mid(
    const int* __restrict__ bsum, int* __restrict__ boff, int* __restrict__ off)
{
    __shared__ int p[128];
    int tid = threadIdx.x;
    int v = (tid < SCAN_NB) ? bsum[tid] : 0;
    p[tid] = v;
    __syncthreads();
#pragma unroll
    for (int o = 1; o < 128; o <<= 1) {
        int t = (tid >= o) ? p[tid - o] : 0;
        __syncthreads();
        p[tid] += t;
        __syncthreads();
    }
    if (tid < SCAN_NB) boff[tid] = p[tid] - v;       // exclusive
    if (tid == 127) off[N_NODES] = p[127];           // grand total
}

// phase C: block-local exclusive scan + block offset
__global__ __launch_bounds__(SCAN_CHUNK) void k_scan_post(
    const int* __restrict__ deg, const int* __restrict__ boff, int* __restrict__ off)
{
    __shared__ int p[SCAN_CHUNK];
    int tid = threadIdx.x;
    int idx = blockIdx.x * SCAN_CHUNK + tid;
    int v = (idx < N_NODES) ? deg[idx] : 0;
    p[tid] = v;
    __syncthreads();
#pragma unroll
    for (int o = 1; o < SCAN_CHUNK; o <<= 1) {
        int t = (tid >= o) ? p[tid - o] : 0;
        __syncthreads();
        p[tid] += t;
        __syncthreads();
    }
    if (idx < N_NODES) off[idx] = boff[blockIdx.x] + p[tid] - v;
}

// --- kernel 4: logits into CSR slots. 8 threads/edge, 32B gather per lane ---
__global__ __launch_bounds__(256) void k_csr_logit(
    const int* __restrict__ ei, const int* __restrict__ epos,
    const int* __restrict__ off, const float* __restrict__ xl,
    const float* __restrict__ xr, const float* __restrict__ att,
    float* __restrict__ csr_logit, int* __restrict__ csr_src)
{
    __shared__ float att_s[64];
    if (threadIdx.x < 64) att_s[threadIdx.x] = att[threadIdx.x];
    __syncthreads();

    int t = blockIdx.x * 256 + threadIdx.x;
    int e = t >> 3;
    if (e >= E_TOT) return;
    int g = t & 7;
    int src, dst;
    if (e < N_EDGES) { src = ei[e]; dst = ei[N_EDGES + e]; }
    else             { src = dst = e - N_EDGES; }

    const float4* a4 = (const float4*)(xl + (size_t)src * 64) + g * 2;
    const float4* b4 = (const float4*)(xr + (size_t)dst * 64) + g * 2;
    const float4* t4 = (const float4*)att_s + g * 2;
    float acc = 0.f;
#pragma unroll
    for (int i = 0; i < 2; ++i) {
        float4 a = a4[i], b = b4[i], tt = t4[i];
        float s;
        s = a.x + b.x; acc = fmaf(tt.x, (s > 0.f ? s : NEG_SLOPE * s), acc);
        s = a.y + b.y; acc = fmaf(tt.y, (s > 0.f ? s : NEG_SLOPE * s), acc);
        s = a.z + b.z; acc = fmaf(tt.z, (s > 0.f ? s : NEG_SLOPE * s), acc);
        s = a.w + b.w; acc = fmaf(tt.w, (s > 0.f ? s : NEG_SLOPE * s), acc);
    }
    acc += __shfl_xor(acc, 1);
    acc += __shfl_xor(acc, 2);
    acc += __shfl_xor(acc, 4);
    if (g == 0) {
        int idx = off[dst] + epos[e];
        csr_logit[idx] = acc;
        csr_src[idx]   = src;
    }
}

// -- kernel 5: per-dst wave: softmax + weighted gather-sum + ELU + logsoftmax --
__global__ __launch_bounds__(256) void k_aggregate(
    const int* __restrict__ off, const int* __restrict__ csr_src,
    const float* __restrict__ csr_logit, const float* __restrict__ xl,
    const float* __restrict__ bias, float* __restrict__ out)
{
    int wid  = (blockIdx.x * 256 + threadIdx.x) >> 6;   // node id (wave-uniform)
    int lane = threadIdx.x & 63;                        // channel
    if (wid >= N_NODES) return;
    int o0 = off[wid], o1 = off[wid + 1];
    int deg = o1 - o0;

    float acc0 = 0.f, acc1 = 0.f, acc2 = 0.f, acc3 = 0.f, ssum;

    if (deg <= 64) {
        float l = (lane < deg) ? csr_logit[o0 + lane] : -INFINITY;
        float m = l;
#pragma unroll
        for (int o = 32; o > 0; o >>= 1) m = fmaxf(m, __shfl_xor(m, o));
        float a = (lane < deg) ? __expf(l - m) : 0.f;
        ssum = a;
#pragma unroll
        for (int o = 32; o > 0; o >>= 1) ssum += __shfl_xor(ssum, o);
        int srcv = (lane < deg) ? csr_src[o0 + lane] : 0;

        int i = 0;
        for (; i + 4 <= deg; i += 4) {
            float a0 = __shfl(a, i),     a1 = __shfl(a, i + 1);
            float a2 = __shfl(a, i + 2), a3 = __shfl(a, i + 3);
            int s0 = __shfl(srcv, i),     s1 = __shfl(srcv, i + 1);
            int s2 = __shfl(srcv, i + 2), s3 = __shfl(srcv, i + 3);
            acc0 = fmaf(a0, xl[(size_t)s0 * 64 + lane], acc0);
            acc1 = fmaf(a1, xl[(size_t)s1 * 64 + lane], acc1);
            acc2 = fmaf(a2, xl[(size_t)s2 * 64 + lane], acc2);
            acc3 = fmaf(a3, xl[(size_t)s3 * 64 + lane], acc3);
        }
        for (; i < deg; ++i) {
            float ai = __shfl(a, i);
            int   si = __shfl(srcv, i);
            acc0 = fmaf(ai, xl[(size_t)si * 64 + lane], acc0);
        }
    } else {  // rare fallback (deg > 64): two-pass, recompute exp
        float m = -INFINITY;
        for (int i = lane; i < deg; i += 64) m = fmaxf(m, csr_logit[o0 + i]);
#pragma unroll
        for (int o = 32; o > 0; o >>= 1) m = fmaxf(m, __shfl_xor(m, o));
        float s0 = 0.f;
        for (int i = lane; i < deg; i += 64) s0 += __expf(csr_logit[o0 + i] - m);
        ssum = s0;
#pragma unroll
        for (int o = 32; o > 0; o >>= 1) ssum += __shfl_xor(ssum, o);
        for (int i = 0; i < deg; ++i) {
            float ai = __expf(csr_logit[o0 + i] - m);
            int   si = csr_src[o0 + i];
            acc0 = fmaf(ai, xl[(size_t)si * 64 + lane], acc0);
        }
    }
    float acc = (acc0 + acc1) + (acc2 + acc3);

    float h = acc / (ssum + 1e-16f) + bias[lane];
    h = (h > 0.f) ? h : (__expf(h) - 1.f);              // ELU
    float mx = h;
#pragma unroll
    for (int o = 32; o > 0; o >>= 1) mx = fmaxf(mx, __shfl_xor(mx, o));
    float ex = __expf(h - mx);
    float sm = ex;
#pragma unroll
    for (int o = 32; o > 0; o >>= 1) sm += __shfl_xor(sm, o);
    out[(size_t)wid * 64 + lane] = h - mx - __logf(sm);
}

extern "C" void kernel_launch(void* const* d_in, const int* in_sizes, int n_in,
                              void* d_out, int out_size, void* d_ws, size_t ws_size,
                              hipStream_t stream)
{
    const float* x    = (const float*)d_in[0];
    const int*   ei   = (const int*)  d_in[1];
    const float* Wl   = (const float*)d_in[2];
    const float* Wr   = (const float*)d_in[3];
    const float* att  = (const float*)d_in[4];
    const float* bias = (const float*)d_in[5];
    float* out = (float*)d_out;

    char* w = (char*)d_ws;
    float* xl        = (float*)w;  w += (size_t)N_NODES * 64 * 4;
    float* xr        = (float*)w;  w += (size_t)N_NODES * 64 * 4;
    float* csr_logit = (float*)w;  w += (size_t)E_TOT * 4;
    int*   csr_src   = (int*)w;    w += (size_t)E_TOT * 4;
    int*   epos      = (int*)w;    w += (size_t)E_TOT * 4;
    int*   deg       = (int*)w;    w += (size_t)N_NODES * 4;
    int*   off       = (int*)w;    w += (size_t)(N_NODES + 1) * 4;
    int*   bsum      = (int*)w;    w += (size_t)SCAN_NB * 4;
    int*   boff      = (int*)w;    w += (size_t)SCAN_NB * 4;

    hipMemsetAsync(deg, 0, (size_t)N_NODES * 4, stream);

    k_gemm     <<<(N_NODES + 31) / 32,        256,        0, stream>>>(x, Wl, Wr, xl, xr);
    k_deg      <<<(E_TOT + 255) / 256,        256,        0, stream>>>(ei, deg, epos);
    k_scan_pre <<<SCAN_NB,                    SCAN_CHUNK, 0, stream>>>(deg, bsum);
    k_scan_mid <<<1,                          128,        0, stream>>>(bsum, boff, off);
    k_scan_post<<<SCAN_NB,                    SCAN_CHUNK, 0, stream>>>(deg, boff, off);
    k_csr_logit<<<(E_TOT * 8 + 255) / 256,    256,        0, stream>>>(ei, epos, off, xl, xr, att, csr_logit, csr_src);
    k_aggregate<<<(N_NODES * 64 + 255) / 256, 256,        0, stream>>>(off, csr_src, csr_logit, xl, bias, out);
}

// Round 4
// 260.692 us; speedup vs baseline: 3.9225x; 1.0815x over previous
//
#include <hip/hip_runtime.h>

#define N_NODES 50000
#define N_EDGES 800000
#define E_TOT   (N_EDGES + N_NODES)   // 850000, self-loops appended at the end
#define IN_C    128
#define OUT_C   64
#define NEG_SLOPE 0.2f

#define SCAN_CHUNK 512
#define SCAN_NB    ((N_NODES + SCAN_CHUNK - 1) / SCAN_CHUNK)   // 98

// ---------------- kernel 1: x_l = x@W_l, x_r = x@W_r (fused) ----------------
__global__ __launch_bounds__(256) void k_gemm(
    const float* __restrict__ x, const float* __restrict__ Wl,
    const float* __restrict__ Wr, float* __restrict__ xl, float* __restrict__ xr)
{
    __shared__ float xs[32 * IN_C];
    const int tid = threadIdx.x;
    const int nbase = blockIdx.x * 32;

    const float4* x4 = (const float4*)x;
    float4* xs4 = (float4*)xs;
    for (int i = tid; i < 1024; i += 256) {
        int row = i >> 5;
        int node = nbase + row;
        float4 v = make_float4(0.f, 0.f, 0.f, 0.f);
        if (node < N_NODES) v = x4[(size_t)node * 32 + (i & 31)];
        xs4[i] = v;
    }
    __syncthreads();

    const int c  = tid & 63;
    const int nb = (tid >> 6) * 8;
    float accl[8], accr[8];
#pragma unroll
    for (int i = 0; i < 8; ++i) { accl[i] = 0.f; accr[i] = 0.f; }

    for (int k = 0; k < IN_C; ++k) {
        float wl = Wl[k * 64 + c];
        float wr = Wr[k * 64 + c];
#pragma unroll
        for (int i = 0; i < 8; ++i) {
            float xv = xs[(nb + i) * IN_C + k];
            accl[i] = fmaf(xv, wl, accl[i]);
            accr[i] = fmaf(xv, wr, accr[i]);
        }
    }
#pragma unroll
    for (int i = 0; i < 8; ++i) {
        int node = nbase + nb + i;
        if (node < N_NODES) {
            xl[(size_t)node * 64 + c] = accl[i];
            xr[(size_t)node * 64 + c] = accr[i];
        }
    }
}

// ---- kernel 2: per-edge degree count; epos[e] = slot within dst segment ----
__global__ __launch_bounds__(256) void k_deg(
    const int* __restrict__ ei, int* __restrict__ deg, int* __restrict__ epos)
{
    int e = blockIdx.x * 256 + threadIdx.x;
    if (e >= E_TOT) return;
    int dst = (e < N_EDGES) ? ei[N_EDGES + e] : e - N_EDGES;
    epos[e] = atomicAdd(&deg[dst], 1);
}

// ---------------- 3-phase multi-block exclusive scan of deg ----------------
__global__ __launch_bounds__(SCAN_CHUNK) void k_scan_pre(
    const int* __restrict__ deg, int* __restrict__ bsum)
{
    __shared__ int red[SCAN_CHUNK];
    int tid = threadIdx.x;
    int idx = blockIdx.x * SCAN_CHUNK + tid;
    red[tid] = (idx < N_NODES) ? deg[idx] : 0;
    __syncthreads();
#pragma unroll
    for (int o = SCAN_CHUNK / 2; o > 0; o >>= 1) {
        if (tid < o) red[tid] += red[tid + o];
        __syncthreads();
    }
    if (tid == 0) bsum[blockIdx.x] = red[0];
}

__global__ __launch_bounds__(128) void k_scan_mid(
    const int* __restrict__ bsum, int* __restrict__ boff, int* __restrict__ off)
{
    __shared__ int p[128];
    int tid = threadIdx.x;
    int v = (tid < SCAN_NB) ? bsum[tid] : 0;
    p[tid] = v;
    __syncthreads();
#pragma unroll
    for (int o = 1; o < 128; o <<= 1) {
        int t = (tid >= o) ? p[tid - o] : 0;
        __syncthreads();
        p[tid] += t;
        __syncthreads();
    }
    if (tid < SCAN_NB) boff[tid] = p[tid] - v;
    if (tid == 127) off[N_NODES] = p[127];
}

__global__ __launch_bounds__(SCAN_CHUNK) void k_scan_post(
    const int* __restrict__ deg, const int* __restrict__ boff, int* __restrict__ off)
{
    __shared__ int p[SCAN_CHUNK];
    int tid = threadIdx.x;
    int idx = blockIdx.x * SCAN_CHUNK + tid;
    int v = (idx < N_NODES) ? deg[idx] : 0;
    p[tid] = v;
    __syncthreads();
#pragma unroll
    for (int o = 1; o < SCAN_CHUNK; o <<= 1) {
        int t = (tid >= o) ? p[tid - o] : 0;
        __syncthreads();
        p[tid] += t;
        __syncthreads();
    }
    if (idx < N_NODES) off[idx] = boff[blockIdx.x] + p[tid] - v;
}

// ------ kernel 4: scatter src ids into CSR slots (index traffic only) ------
__global__ __launch_bounds__(256) void k_csr_fill(
    const int* __restrict__ ei, const int* __restrict__ epos,
    const int* __restrict__ off, int* __restrict__ csr_src)
{
    int e = blockIdx.x * 256 + threadIdx.x;
    if (e >= E_TOT) return;
    int src, dst;
    if (e < N_EDGES) { src = ei[e]; dst = ei[N_EDGES + e]; }
    else             { src = dst = e - N_EDGES; }
    csr_src[off[dst] + epos[e]] = src;
}

// --- kernel 5: fused logit + online softmax + gather-sum + ELU + logsoftmax ---
// one 64-lane wave per dst node; lane = output channel; xl row read ONCE/edge
__global__ __launch_bounds__(256) void k_fused(
    const int* __restrict__ off, const int* __restrict__ csr_src,
    const float* __restrict__ xl, const float* __restrict__ xr,
    const float* __restrict__ att, const float* __restrict__ bias,
    float* __restrict__ out)
{
    int wid  = (blockIdx.x * 256 + threadIdx.x) >> 6;   // node id (wave-uniform)
    int lane = threadIdx.x & 63;                        // channel
    if (wid >= N_NODES) return;
    int o0 = off[wid], o1 = off[wid + 1];

    float xrv  = xr[(size_t)wid * 64 + lane];
    float attv = att[lane];

    float m = -INFINITY, s = 0.f, acc = 0.f;

    // 2-deep prefetch of gathered xl rows
    int sa, sb; float v0 = 0.f, v1 = 0.f;
    int i = o0;
    if (i < o1)     { sa = csr_src[i];     v0 = xl[(size_t)sa * 64 + lane]; }
    if (i + 1 < o1) { sb = csr_src[i + 1]; v1 = xl[(size_t)sb * 64 + lane]; }

    while (i + 2 <= o1) {
        float va = v0, vb = v1;
        if (i + 2 < o1) { sa = csr_src[i + 2]; v0 = xl[(size_t)sa * 64 + lane]; }
        if (i + 3 < o1) { sb = csr_src[i + 3]; v1 = xl[(size_t)sb * 64 + lane]; }

        float ta = va + xrv; ta = (ta > 0.f) ? ta : NEG_SLOPE * ta;
        float tb = vb + xrv; tb = (tb > 0.f) ? tb : NEG_SLOPE * tb;
        float la = attv * ta;
        float lb = attv * tb;
#pragma unroll
        for (int o = 32; o > 0; o >>= 1) {   // two independent reduce chains
            la += __shfl_xor(la, o);
            lb += __shfl_xor(lb, o);
        }
        float mn = fmaxf(m, la);
        float corr = __expf(m - mn);
        float w = __expf(la - mn);
        s = s * corr + w;
        acc = fmaf(w, va, acc * corr);
        m = mn;

        mn = fmaxf(m, lb);
        corr = __expf(m - mn);
        w = __expf(lb - mn);
        s = s * corr + w;
        acc = fmaf(w, vb, acc * corr);
        m = mn;

        i += 2;
    }
    if (i < o1) {   // odd tail
        float va = v0;
        float ta = va + xrv; ta = (ta > 0.f) ? ta : NEG_SLOPE * ta;
        float la = attv * ta;
#pragma unroll
        for (int o = 32; o > 0; o >>= 1) la += __shfl_xor(la, o);
        float mn = fmaxf(m, la);
        float corr = __expf(m - mn);
        float w = __expf(la - mn);
        s = s * corr + w;
        acc = fmaf(w, va, acc * corr);
    }

    float h = acc / (s + 1e-16f) + bias[lane];
    h = (h > 0.f) ? h : (__expf(h) - 1.f);              // ELU
    float mx = h;
#pragma unroll
    for (int o = 32; o > 0; o >>= 1) mx = fmaxf(mx, __shfl_xor(mx, o));
    float ex = __expf(h - mx);
    float sm = ex;
#pragma unroll
    for (int o = 32; o > 0; o >>= 1) sm += __shfl_xor(sm, o);
    out[(size_t)wid * 64 + lane] = h - mx - __logf(sm);
}

extern "C" void kernel_launch(void* const* d_in, const int* in_sizes, int n_in,
                              void* d_out, int out_size, void* d_ws, size_t ws_size,
                              hipStream_t stream)
{
    const float* x    = (const float*)d_in[0];
    const int*   ei   = (const int*)  d_in[1];
    const float* Wl   = (const float*)d_in[2];
    const float* Wr   = (const float*)d_in[3];
    const float* att  = (const float*)d_in[4];
    const float* bias = (const float*)d_in[5];
    float* out = (float*)d_out;

    char* w = (char*)d_ws;
    float* xl      = (float*)w;  w += (size_t)N_NODES * 64 * 4;
    float* xr      = (float*)w;  w += (size_t)N_NODES * 64 * 4;
    int*   csr_src = (int*)w;    w += (size_t)E_TOT * 4;
    int*   epos    = (int*)w;    w += (size_t)E_TOT * 4;
    int*   deg     = (int*)w;    w += (size_t)N_NODES * 4;
    int*   off     = (int*)w;    w += (size_t)(N_NODES + 1) * 4;
    int*   bsum    = (int*)w;    w += (size_t)SCAN_NB * 4;
    int*   boff    = (int*)w;    w += (size_t)SCAN_NB * 4;

    hipMemsetAsync(deg, 0, (size_t)N_NODES * 4, stream);

    k_gemm     <<<(N_NODES + 31) / 32,        256,        0, stream>>>(x, Wl, Wr, xl, xr);
    k_deg      <<<(E_TOT + 255) / 256,        256,        0, stream>>>(ei, deg, epos);
    k_scan_pre <<<SCAN_NB,                    SCAN_CHUNK, 0, stream>>>(deg, bsum);
    k_scan_mid <<<1,                          128,        0, stream>>>(bsum, boff, off);
    k_scan_post<<<SCAN_NB,                    SCAN_CHUNK, 0, stream>>>(deg, boff, off);
    k_csr_fill <<<(E_TOT + 255) / 256,        256,        0, stream>>>(ei, epos, off, csr_src);
    k_fused    <<<(N_NODES * 64 + 255) / 256, 256,        0, stream>>>(off, csr_src, xl, xr, att, bias, out);
}